// Round 2
// baseline (355.859 us; speedup 1.0000x reference)
//
#include <hip/hip_runtime.h>
#include <hip/hip_bf16.h>
#include <stdint.h>

#define IN_F   4096
#define OUT_F  4096
#define M_ROWS 2048
#define LORA_SCALE 2.0f   // 32.0 / 16

typedef __bf16 bf16x8 __attribute__((ext_vector_type(8)));
typedef float  f32x4  __attribute__((ext_vector_type(4)));

typedef const __attribute__((address_space(1))) void gvoid_t;
typedef __attribute__((address_space(3))) void lvoid_t;

// ---------- 1. fused: dequant 4-bit -> bf16 W, and x fp32 -> bf16
__global__ void prep_kernel(const int* __restrict__ qw,
                            const float* __restrict__ scales,
                            __hip_bfloat16* __restrict__ W,
                            const float* __restrict__ x,
                            __hip_bfloat16* __restrict__ xb) {
    int b = blockIdx.x;
    if (b < 8192) {
        // dequant: 4 packed bytes (stored one per int32) -> 8 bf16 weights
        int t = b * 256 + threadIdx.x;
        int4 q = ((const int4*)qw)[t];
        float scale = scales[t >> 3];           // 32 packed bytes per 64-weight block
        float step = scale * (2.0f / 15.0f);
        int bb[4] = {q.x, q.y, q.z, q.w};
        union { __hip_bfloat16 h[8]; uint4 v; } o;
        #pragma unroll
        for (int j = 0; j < 4; ++j) {
            float lo = (float)(bb[j] & 15)        * step - scale;
            float hi = (float)((bb[j] >> 4) & 15) * step - scale;
            o.h[2*j]   = __float2bfloat16(lo);
            o.h[2*j+1] = __float2bfloat16(hi);
        }
        ((uint4*)W)[t] = o.v;
    } else {
        // xcast: 8 floats -> 8 bf16 per thread
        int t = (b - 8192) * 256 + threadIdx.x;
        float4 a = ((const float4*)x)[2*t];
        float4 c = ((const float4*)x)[2*t + 1];
        union { __hip_bfloat16 h[8]; uint4 v; } o;
        o.h[0] = __float2bfloat16(a.x); o.h[1] = __float2bfloat16(a.y);
        o.h[2] = __float2bfloat16(a.z); o.h[3] = __float2bfloat16(a.w);
        o.h[4] = __float2bfloat16(c.x); o.h[5] = __float2bfloat16(c.y);
        o.h[6] = __float2bfloat16(c.z); o.h[7] = __float2bfloat16(c.w);
        ((uint4*)xb)[t] = o.v;
    }
}

// ---------- 2. t[m][r] = sum_k x[m][k] * A[r][k]   (fp32 exact)
__global__ void lora_t_kernel(const float* __restrict__ x,
                              const float* __restrict__ A,
                              float* __restrict__ tout) {
    __shared__ float red[16 * 4 * 16];          // [g][row][r]
    int m0 = blockIdx.x * 4;
    int r = threadIdx.x & 15;
    int g = threadIdx.x >> 4;
    float acc[4] = {0.f, 0.f, 0.f, 0.f};
    for (int kb = 0; kb < 64; ++kb) {
        int k = kb * 64 + g * 4;
        float4 av = *(const float4*)(A + (size_t)r * IN_F + k);
        #pragma unroll
        for (int row = 0; row < 4; ++row) {
            float4 xv = *(const float4*)(x + (size_t)(m0 + row) * IN_F + k);
            acc[row] += xv.x*av.x + xv.y*av.y + xv.z*av.z + xv.w*av.w;
        }
    }
    #pragma unroll
    for (int row = 0; row < 4; ++row) red[g*64 + row*16 + r] = acc[row];
    __syncthreads();
    if (threadIdx.x < 64) {
        int row = threadIdx.x >> 4, rr = threadIdx.x & 15;
        float s = 0.f;
        #pragma unroll
        for (int gg = 0; gg < 16; ++gg) s += red[gg*64 + row*16 + rr];
        tout[(size_t)(m0 + row) * 16 + rr] = s;
    }
}

// ---------- 3. GEMM: out[m][n] = sum_k Xb[m][k]*W[n][k] + bias[n] + 2*dot(t[m],loraB[n])
// 512 threads = 8 waves; 128x128 tile; per-wave 2x4 of 16x16x32 MFMA tiles.
// Double-buffered LDS, one barrier per K-iteration.
__global__ __launch_bounds__(512, 4) void gemm_kernel(
        const __hip_bfloat16* __restrict__ A,     // [M, K] bf16
        const __hip_bfloat16* __restrict__ B,     // [N, K] bf16 (= W)
        const float* __restrict__ bias,           // [N]
        const float* __restrict__ loraB,          // [N, 16]
        const float* __restrict__ tmat,           // [M, 16]
        float* __restrict__ out) {                // [M, N]
    const int K = IN_F, N = OUT_F;
    __shared__ union alignas(16) {
        struct { __hip_bfloat16 As[2][128*32]; __hip_bfloat16 Bs[2][128*32]; } s; // 32 KB
        float tstage[128 * 16];                                                   // 8 KB
    } sm;

    int tid  = threadIdx.x;
    int wave = tid >> 6, lane = tid & 63;
    int wm = wave >> 1, wn = wave & 1;            // wm 0..3 (32 rows), wn 0..1 (64 cols)
    int row16 = lane & 15, quad = lane >> 4;
    int m0 = blockIdx.y * 128, n0 = blockIdx.x * 128;

    int srow = lane >> 2;          // 0..15 within this wave's 16-row segment
    int scol = (lane & 3) * 8;     // 0,8,16,24

    // each wave stages A-segment `wave` (16 rows x 32 cols) and B-segment `wave`
    const __hip_bfloat16* gA0 = A + (size_t)(m0 + wave*16 + srow) * K + scol;
    const __hip_bfloat16* gB0 = B + (size_t)(n0 + wave*16 + srow) * K + scol;

    f32x4 acc[2][4];
    #pragma unroll
    for (int i = 0; i < 2; ++i)
        #pragma unroll
        for (int j = 0; j < 4; ++j) acc[i][j] = (f32x4){0.f, 0.f, 0.f, 0.f};

    // prologue: stage k0=0 into buffer 0
    __builtin_amdgcn_global_load_lds((gvoid_t*)gA0, (lvoid_t*)&sm.s.As[0][wave*512], 16, 0, 0);
    __builtin_amdgcn_global_load_lds((gvoid_t*)gB0, (lvoid_t*)&sm.s.Bs[0][wave*512], 16, 0, 0);
    __syncthreads();

    for (int k0 = 0; k0 < K; k0 += 32) {
        int cur = (k0 >> 5) & 1;
        if (k0 + 32 < K) {   // prefetch next K-slab into the other buffer
            __builtin_amdgcn_global_load_lds((gvoid_t*)(gA0 + k0 + 32),
                (lvoid_t*)&sm.s.As[cur^1][wave*512], 16, 0, 0);
            __builtin_amdgcn_global_load_lds((gvoid_t*)(gB0 + k0 + 32),
                (lvoid_t*)&sm.s.Bs[cur^1][wave*512], 16, 0, 0);
        }

        bf16x8 af[2], bfr[4];
        #pragma unroll
        for (int mt = 0; mt < 2; ++mt)
            af[mt] = *(const bf16x8*)&sm.s.As[cur][(wm*32 + mt*16 + row16)*32 + quad*8];
        #pragma unroll
        for (int nt = 0; nt < 4; ++nt)
            bfr[nt] = *(const bf16x8*)&sm.s.Bs[cur][(wn*64 + nt*16 + row16)*32 + quad*8];
        #pragma unroll
        for (int mt = 0; mt < 2; ++mt)
            #pragma unroll
            for (int nt = 0; nt < 4; ++nt)
                acc[mt][nt] = __builtin_amdgcn_mfma_f32_16x16x32_bf16(
                    af[mt], bfr[nt], acc[mt][nt], 0, 0, 0);

        __syncthreads();   // single barrier: protects both buffer reuse and prefetch arrival
    }

    // stage t rows for this m-block into (reused) LDS: 128 x 16 fp32
    ((float4*)sm.tstage)[tid] = ((const float4*)(tmat + (size_t)m0 * 16))[tid];
    __syncthreads();

    #pragma unroll
    for (int nt = 0; nt < 4; ++nt) {
        int nl = wn*64 + nt*16 + row16;
        int n  = n0 + nl;
        float bn = bias[n];
        const float4* lb = (const float4*)(loraB + (size_t)n * 16);
        float4 lb0 = lb[0], lb1 = lb[1], lb2 = lb[2], lb3 = lb[3];
        #pragma unroll
        for (int mt = 0; mt < 2; ++mt) {
            #pragma unroll
            for (int r = 0; r < 4; ++r) {
                int ml = wm*32 + mt*16 + quad*4 + r;
                const float* tm = &sm.tstage[ml * 16];
                float dot =
                    tm[0]*lb0.x + tm[1]*lb0.y + tm[2]*lb0.z + tm[3]*lb0.w +
                    tm[4]*lb1.x + tm[5]*lb1.y + tm[6]*lb1.z + tm[7]*lb1.w +
                    tm[8]*lb2.x + tm[9]*lb2.y + tm[10]*lb2.z + tm[11]*lb2.w +
                    tm[12]*lb3.x + tm[13]*lb3.y + tm[14]*lb3.z + tm[15]*lb3.w;
                out[(size_t)(m0 + ml) * N + n] = acc[mt][nt][r] + bn + LORA_SCALE * dot;
            }
        }
    }
}

extern "C" void kernel_launch(void* const* d_in, const int* in_sizes, int n_in,
                              void* d_out, int out_size, void* d_ws, size_t ws_size,
                              hipStream_t stream) {
    const float* x      = (const float*)d_in[0];   // [2,1024,4096]
    const int*   qw     = (const int*)d_in[1];     // [8388608] one byte each
    const float* scales = (const float*)d_in[2];   // [262144]
    const float* bias   = (const float*)d_in[3];   // [4096]
    const float* loraA  = (const float*)d_in[4];   // [16,4096]
    const float* loraB  = (const float*)d_in[5];   // [4096,16]
    float* out = (float*)d_out;

    char* ws = (char*)d_ws;
    __hip_bfloat16* Wb = (__hip_bfloat16*)ws;                           // 33,554,432 B
    __hip_bfloat16* Xb = (__hip_bfloat16*)(ws + 33554432);              // 16,777,216 B
    float* tmat        = (float*)(ws + 33554432 + 16777216);            //    131,072 B

    prep_kernel  <<<12288, 256, 0, stream>>>(qw, scales, Wb, x, Xb);
    lora_t_kernel<<<512,  256, 0, stream>>>(x, loraA, tmat);
    gemm_kernel  <<<dim3(32, 16), 512, 0, stream>>>(Xb, Wb, bias, loraB, tmat, out);
}

// Round 3
// 304.788 us; speedup vs baseline: 1.1676x; 1.1676x over previous
//
#include <hip/hip_runtime.h>
#include <hip/hip_bf16.h>
#include <stdint.h>

#define IN_F   4096
#define OUT_F  4096
#define M_ROWS 2048
#define LORA_SCALE 2.0f   // 32.0 / 16

typedef __bf16 bf16x8 __attribute__((ext_vector_type(8)));
typedef float  f32x4  __attribute__((ext_vector_type(4)));

typedef const __attribute__((address_space(1))) void gvoid_t;
typedef __attribute__((address_space(3))) void lvoid_t;

// ---------- 1. fused prep: dequant W -> bf16, cast x -> bf16, t = x@A^T (fp32)
__global__ void prep_kernel(const int* __restrict__ qw,
                            const float* __restrict__ scales,
                            __hip_bfloat16* __restrict__ W,
                            const float* __restrict__ x,
                            __hip_bfloat16* __restrict__ xb,
                            const float* __restrict__ A,
                            float* __restrict__ tout) {
    int b = blockIdx.x;
    if (b < 8192) {
        // dequant: 4 packed bytes (one per int32) -> 8 bf16 weights
        int t = b * 256 + threadIdx.x;
        int4 q = ((const int4*)qw)[t];
        float scale = scales[t >> 3];           // 32 packed bytes per 64-weight block
        float step = scale * (2.0f / 15.0f);
        int bb[4] = {q.x, q.y, q.z, q.w};
        union { __hip_bfloat16 h[8]; uint4 v; } o;
        #pragma unroll
        for (int j = 0; j < 4; ++j) {
            float lo = (float)(bb[j] & 15)        * step - scale;
            float hi = (float)((bb[j] >> 4) & 15) * step - scale;
            o.h[2*j]   = __float2bfloat16(lo);
            o.h[2*j+1] = __float2bfloat16(hi);
        }
        ((uint4*)W)[t] = o.v;
    } else if (b < 12288) {
        // xcast: 8 floats -> 8 bf16 per thread
        int t = (b - 8192) * 256 + threadIdx.x;
        float4 a = ((const float4*)x)[2*t];
        float4 c = ((const float4*)x)[2*t + 1];
        union { __hip_bfloat16 h[8]; uint4 v; } o;
        o.h[0] = __float2bfloat16(a.x); o.h[1] = __float2bfloat16(a.y);
        o.h[2] = __float2bfloat16(a.z); o.h[3] = __float2bfloat16(a.w);
        o.h[4] = __float2bfloat16(c.x); o.h[5] = __float2bfloat16(c.y);
        o.h[6] = __float2bfloat16(c.z); o.h[7] = __float2bfloat16(c.w);
        ((uint4*)xb)[t] = o.v;
    } else {
        // lora t[m][r] = sum_k x[m][k]*A[r][k], 4 rows per block
        __shared__ float red[16 * 4 * 16];
        int m0 = (b - 12288) * 4;
        int r = threadIdx.x & 15;
        int g = threadIdx.x >> 4;
        float acc[4] = {0.f, 0.f, 0.f, 0.f};
        for (int kb = 0; kb < 64; ++kb) {
            int k = kb * 64 + g * 4;
            float4 av = *(const float4*)(A + (size_t)r * IN_F + k);
            #pragma unroll
            for (int row = 0; row < 4; ++row) {
                float4 xv = *(const float4*)(x + (size_t)(m0 + row) * IN_F + k);
                acc[row] += xv.x*av.x + xv.y*av.y + xv.z*av.z + xv.w*av.w;
            }
        }
        #pragma unroll
        for (int row = 0; row < 4; ++row) red[g*64 + row*16 + r] = acc[row];
        __syncthreads();
        if (threadIdx.x < 64) {
            int row = threadIdx.x >> 4, rr = threadIdx.x & 15;
            float s = 0.f;
            #pragma unroll
            for (int gg = 0; gg < 16; ++gg) s += red[gg*64 + row*16 + rr];
            tout[(size_t)(m0 + row) * 16 + rr] = s;
        }
    }
}

// ---------- 2. GEMM: out = Xb @ Wb^T + bias + 2*(t @ loraB^T)
// 256 threads = 4 waves; 64x128 tile; per-wave 2x4 of 16x16x32 MFMA tiles.
// BK=64, XOR-swizzled LDS (conflict-free b128 reads), double-buffered, 1 barrier/iter.
__global__ __launch_bounds__(256, 2) void gemm_kernel(
        const __hip_bfloat16* __restrict__ A,     // [M, K] bf16
        const __hip_bfloat16* __restrict__ B,     // [N, K] bf16 (= W)
        const float* __restrict__ bias,           // [N]
        const float* __restrict__ loraB,          // [N, 16]
        const float* __restrict__ tmat,           // [M, 16]
        float* __restrict__ out) {                // [M, N]
    const int K = IN_F, N = OUT_F;
    __shared__ union alignas(16) {
        struct { __hip_bfloat16 As[2][64*64]; __hip_bfloat16 Bs[2][128*64]; } s; // 48 KB
        float tstage[64 * 16];                                                   //  4 KB
    } sm;

    int tid  = threadIdx.x;
    int wave = tid >> 6, lane = tid & 63;
    int wm = wave >> 1, wn = wave & 1;            // wm: 32-row half, wn: 64-col half
    int row16 = lane & 15, quad = lane >> 4;
    int r7 = row16 & 7;                           // swizzle key (matches writer's row&7)
    int m0 = blockIdx.y * 64, n0 = blockIdx.x * 128;

    // DMA source mapping: lane i covers row (seg*8 + i>>3), 16B-chunk ((i&7) ^ (i>>3 & 7))
    int rl = lane >> 3;                // 0..7 row-within-segment
    int cg = (lane & 7) ^ rl;          // swizzled global chunk (16B units)

    // A: 8 segments of 8 rows; wave stages segs {wave*2, wave*2+1}
    const __hip_bfloat16* pA = A + (size_t)(m0 + wave*16 + rl) * K + cg*8;
    // B: 16 segments of 8 rows; wave stages segs {wave*4 .. wave*4+3}
    const __hip_bfloat16* pB = B + (size_t)(n0 + wave*32 + rl) * K + cg*8;

    f32x4 acc[2][4];
    #pragma unroll
    for (int i = 0; i < 2; ++i)
        #pragma unroll
        for (int j = 0; j < 4; ++j) acc[i][j] = (f32x4){0.f, 0.f, 0.f, 0.f};

    // prologue: stage k0=0 into buffer 0
    #pragma unroll
    for (int j = 0; j < 2; ++j)
        __builtin_amdgcn_global_load_lds((gvoid_t*)(pA + (size_t)j*8*K),
            (lvoid_t*)&sm.s.As[0][(wave*2 + j) * 512], 16, 0, 0);
    #pragma unroll
    for (int j = 0; j < 4; ++j)
        __builtin_amdgcn_global_load_lds((gvoid_t*)(pB + (size_t)j*8*K),
            (lvoid_t*)&sm.s.Bs[0][(wave*4 + j) * 512], 16, 0, 0);
    __syncthreads();

    for (int k0 = 0; k0 < K; k0 += 64) {
        int cur = (k0 >> 6) & 1;
        if (k0 + 64 < K) {   // prefetch next slab into other buffer (flies during compute)
            #pragma unroll
            for (int j = 0; j < 2; ++j)
                __builtin_amdgcn_global_load_lds((gvoid_t*)(pA + k0 + 64 + (size_t)j*8*K),
                    (lvoid_t*)&sm.s.As[cur^1][(wave*2 + j) * 512], 16, 0, 0);
            #pragma unroll
            for (int j = 0; j < 4; ++j)
                __builtin_amdgcn_global_load_lds((gvoid_t*)(pB + k0 + 64 + (size_t)j*8*K),
                    (lvoid_t*)&sm.s.Bs[cur^1][(wave*4 + j) * 512], 16, 0, 0);
        }

        #pragma unroll
        for (int s = 0; s < 2; ++s) {            // two 16x16x32 k-steps per 64-k slab
            bf16x8 af[2], bfr[4];
            #pragma unroll
            for (int mt = 0; mt < 2; ++mt) {
                int row = wm*32 + mt*16 + row16;
                af[mt] = *(const bf16x8*)&sm.s.As[cur][row*64 + ((s*4 + quad) ^ r7) * 8];
            }
            #pragma unroll
            for (int nt = 0; nt < 4; ++nt) {
                int row = wn*64 + nt*16 + row16;
                bfr[nt] = *(const bf16x8*)&sm.s.Bs[cur][row*64 + ((s*4 + quad) ^ r7) * 8];
            }
            #pragma unroll
            for (int mt = 0; mt < 2; ++mt)
                #pragma unroll
                for (int nt = 0; nt < 4; ++nt)
                    acc[mt][nt] = __builtin_amdgcn_mfma_f32_16x16x32_bf16(
                        af[mt], bfr[nt], acc[mt][nt], 0, 0, 0);
        }

        __syncthreads();   // protects buffer reuse + prefetch arrival
    }

    // stage t rows for this m-block: 64 x 16 fp32 = 256 float4 (one per thread)
    ((float4*)sm.tstage)[tid] = ((const float4*)(tmat + (size_t)m0 * 16))[tid];
    __syncthreads();

    #pragma unroll
    for (int nt = 0; nt < 4; ++nt) {
        int nl = wn*64 + nt*16 + row16;
        int n  = n0 + nl;
        float bn = bias[n];
        const float4* lb = (const float4*)(loraB + (size_t)n * 16);
        float4 lb0 = lb[0], lb1 = lb[1], lb2 = lb[2], lb3 = lb[3];
        #pragma unroll
        for (int mt = 0; mt < 2; ++mt) {
            #pragma unroll
            for (int r = 0; r < 4; ++r) {
                int ml = wm*32 + mt*16 + quad*4 + r;
                const float* tm = &sm.tstage[ml * 16];
                float dot =
                    tm[0]*lb0.x + tm[1]*lb0.y + tm[2]*lb0.z + tm[3]*lb0.w +
                    tm[4]*lb1.x + tm[5]*lb1.y + tm[6]*lb1.z + tm[7]*lb1.w +
                    tm[8]*lb2.x + tm[9]*lb2.y + tm[10]*lb2.z + tm[11]*lb2.w +
                    tm[12]*lb3.x + tm[13]*lb3.y + tm[14]*lb3.z + tm[15]*lb3.w;
                out[(size_t)(m0 + ml) * N + n] = acc[mt][nt][r] + bn + LORA_SCALE * dot;
            }
        }
    }
}

extern "C" void kernel_launch(void* const* d_in, const int* in_sizes, int n_in,
                              void* d_out, int out_size, void* d_ws, size_t ws_size,
                              hipStream_t stream) {
    const float* x      = (const float*)d_in[0];   // [2,1024,4096]
    const int*   qw     = (const int*)d_in[1];     // [8388608] one byte each
    const float* scales = (const float*)d_in[2];   // [262144]
    const float* bias   = (const float*)d_in[3];   // [4096]
    const float* loraA  = (const float*)d_in[4];   // [16,4096]
    const float* loraB  = (const float*)d_in[5];   // [4096,16]
    float* out = (float*)d_out;

    char* ws = (char*)d_ws;
    __hip_bfloat16* Wb = (__hip_bfloat16*)ws;                           // 33,554,432 B
    __hip_bfloat16* Xb = (__hip_bfloat16*)(ws + 33554432);              // 16,777,216 B
    float* tmat        = (float*)(ws + 33554432 + 16777216);            //    131,072 B

    prep_kernel<<<12800, 256, 0, stream>>>(qw, scales, Wb, x, Xb, loraA, tmat);
    gemm_kernel<<<dim3(32, 32), 256, 0, stream>>>(Xb, Wb, bias, loraB, tmat, out);
}